// Round 5
// baseline (217.235 us; speedup 1.0000x reference)
//
#include <hip/hip_runtime.h>

#define N_CTX 2048
#define DHEAD 64
#define SCALE_F 0.125f
#define EPS_F 1e-6f
#define KT 64
#define NITER (N_CTX / KT)
#define QBLK 128           // q per block: 4 waves x 32 q

typedef __attribute__((ext_vector_type(8))) short short8;
typedef __attribute__((ext_vector_type(4))) short short4v;
typedef __attribute__((ext_vector_type(4))) float float4v;
typedef __attribute__((ext_vector_type(2))) unsigned uint2v;
typedef __attribute__((ext_vector_type(4))) unsigned uint4v;

// ---- bf16 pack: HW cvt_pk on device, parse-only fallback for host pass ----
#if defined(__HIP_DEVICE_COMPILE__) && __has_builtin(__builtin_amdgcn_cvt_pk_bf16_f32)
typedef __attribute__((ext_vector_type(2))) __bf16 bf16x2;
__device__ __forceinline__ unsigned pack2(float a, float b) {
    union { bf16x2 v; unsigned u; } x;
    x.v = __builtin_amdgcn_cvt_pk_bf16_f32(a, b);
    return x.u;
}
#else
__device__ __forceinline__ unsigned bf1(float f) {
    union { float f; unsigned u; } x; x.f = f;
    return (x.u + 0x7FFFu + ((x.u >> 16) & 1u)) >> 16;
}
__device__ __forceinline__ unsigned pack2(float a, float b) {
    return bf1(a) | (bf1(b) << 16);
}
#endif

// ---- K=16 bf16 MFMA (A,B = 4 bf16/lane; C/D = float4) ----
#if defined(__HIP_DEVICE_COMPILE__)
  #if __has_builtin(__builtin_amdgcn_mfma_f32_16x16x16bf16_1k)
    #define MFMA16(a, b, c) __builtin_amdgcn_mfma_f32_16x16x16bf16_1k(a, b, c, 0, 0, 0)
  #elif __has_builtin(__builtin_amdgcn_mfma_f32_16x16x16_bf16_1k)
    #define MFMA16(a, b, c) __builtin_amdgcn_mfma_f32_16x16x16_bf16_1k(a, b, c, 0, 0, 0)
  #else
    __device__ __forceinline__ float4v mfma16_asm(short4v a, short4v b, float4v c) {
        asm volatile("v_mfma_f32_16x16x16_bf16 %0, %1, %2, %0"
                     : "+v"(c) : "v"(a), "v"(b));
        return c;
    }
    #define MFMA16(a, b, c) mfma16_asm(a, b, c)
  #endif
#else
  #define MFMA16(a, b, c) (c)   /* host pass: parse-only, never executed */
#endif

// Layouts (gfx950, m89-verified):
//  mfma 16x16x32: A[m=lane&15][k=8q+j], B[k=8q+j][n=lane&15], C[row=4q+r][col=lane&15]
//  mfma 16x16x16: A[m=lane&15][k=4q+j], B[k=4q+j][n=lane&15]  (q = lane>>4)
// S^T = K*Q^T: its C-layout rows kv=4q+r equal the K=16 A-frag k=4q+j ->
// square in registers, pack, feed PV with zero data movement.

__global__ __launch_bounds__(256, 3)
void powsm_attn(const float* __restrict__ qg, const float* __restrict__ kg,
                const float* __restrict__ vg, float* __restrict__ og)
{
    __shared__ short Ks[2][64][72];   // K tile row-major bf16, double-buffered
    __shared__ short Vt[2][64][68];   // V transposed Vt[d][kv], double-buffered
    __shared__ float Dn[4][32];       // per-wave denominator exchange

    // XCD swizzle: blocks with the same bh land on the same XCD (i%8 const).
    const int i     = blockIdx.x;
    const int bh    = (i & 7) * 8 + ((i >> 3) & 7);
    const int qtile = i >> 6;

    const int tid  = threadIdx.x;
    const int wave = tid >> 6;
    const int lane = tid & 63;
    const int qd   = lane >> 4;    // quad 0..3
    const int c    = lane & 15;

    const size_t base = (size_t)bh * N_CTX * DHEAD;
    const float* qp = qg + base;
    const float* kp = kg + base;
    const float* vp = vg + base;
    float*       op = og + base;

    const int qw0 = qtile * QBLK + wave * 32;

    // ---- hoist Q B-frags (16x16x32), SCALE folded in ----
    short8 Qf[2][2];
    #pragma unroll
    for (int qt = 0; qt < 2; ++qt) {
        #pragma unroll
        for (int ks = 0; ks < 2; ++ks) {
            const float* src = qp + (size_t)(qw0 + qt*16 + c) * DHEAD + ks*32 + qd*8;
            float4v a = *(const float4v*)(src);
            float4v b = *(const float4v*)(src + 4);
            uint4v u;
            u[0] = pack2(a[0]*SCALE_F, a[1]*SCALE_F);
            u[1] = pack2(a[2]*SCALE_F, a[3]*SCALE_F);
            u[2] = pack2(b[0]*SCALE_F, b[1]*SCALE_F);
            u[3] = pack2(b[2]*SCALE_F, b[3]*SCALE_F);
            union { uint4v u; short8 s; } cv; cv.u = u;
            Qf[qt][ks] = cv.s;
        }
    }

    float4v Oacc[2][4];            // [qt][nt]
    #pragma unroll
    for (int qt = 0; qt < 2; ++qt)
        #pragma unroll
        for (int nt = 0; nt < 4; ++nt)
            Oacc[qt][nt] = (float4v){0.f, 0.f, 0.f, 0.f};
    float4v dacc[2];
    dacc[0] = (float4v){0.f, 0.f, 0.f, 0.f};
    dacc[1] = (float4v){0.f, 0.f, 0.f, 0.f};

    // ---- staging mapping (all 256 threads stage both K and V) ----
    const int sr = tid >> 4;       // 0..15
    const int sc = tid & 15;       // 0..15

    float4v pK[4], pV[4];

    #define LOAD_TILE(t)                                                        \
        do {                                                                    \
            const float* kn_ = kp + (size_t)(t) * KT * DHEAD;                   \
            const float* vn_ = vp + (size_t)(t) * KT * DHEAD;                   \
            _Pragma("unroll")                                                   \
            for (int u_ = 0; u_ < 4; ++u_)                                      \
                pK[u_] = *(const float4v*)(kn_ + (size_t)(sr + u_*16) * DHEAD + sc*4); \
            _Pragma("unroll")                                                   \
            for (int j_ = 0; j_ < 4; ++j_)                                      \
                pV[j_] = *(const float4v*)(vn_ + (size_t)(4*sr + j_) * DHEAD + sc*4);  \
        } while (0)

    #define STAGE_TILE(buf)                                                     \
        do {                                                                    \
            _Pragma("unroll")                                                   \
            for (int u_ = 0; u_ < 4; ++u_) {                                    \
                uint2v w_; w_[0] = pack2(pK[u_][0], pK[u_][1]);                 \
                           w_[1] = pack2(pK[u_][2], pK[u_][3]);                 \
                *(uint2v*)&Ks[buf][sr + u_*16][sc*4] = w_;                      \
            }                                                                   \
            _Pragma("unroll")                                                   \
            for (int kk_ = 0; kk_ < 4; ++kk_) {                                 \
                uint2v w_; w_[0] = pack2(pV[0][kk_], pV[1][kk_]);               \
                           w_[1] = pack2(pV[2][kk_], pV[3][kk_]);               \
                *(uint2v*)&Vt[buf][4*sc + kk_][4*sr] = w_;                      \
            }                                                                   \
        } while (0)

    // ---- prologue: tile 0 staged, tile 1 in flight ----
    LOAD_TILE(0);
    STAGE_TILE(0);
    LOAD_TILE(1);
    __syncthreads();

    #pragma unroll 1
    for (int kvi = 0; kvi < NITER; ++kvi) {
        const int cur = kvi & 1;

        // stage tile kvi+1 into the other buffer (writes drain during compute,
        // enforced only at the single end-of-iter barrier)
        if (kvi + 1 < NITER) STAGE_TILE(cur ^ 1);
        // prefetch tile kvi+2 (consumed after compute + barrier -> full slack)
        if (kvi + 2 < NITER) LOAD_TILE(kvi + 2);

        // ---- compute on buffer `cur`: S^T -> square -> PV, all in registers ----
        #pragma unroll
        for (int mt = 0; mt < 4; ++mt) {
            float4v s[2];
            s[0] = (float4v){0.f, 0.f, 0.f, 0.f};
            s[1] = (float4v){0.f, 0.f, 0.f, 0.f};
            #pragma unroll
            for (int ks = 0; ks < 2; ++ks) {
                short8 af = *(const short8*)&Ks[cur][mt*16 + c][ks*32 + qd*8];
                #pragma unroll
                for (int qt = 0; qt < 2; ++qt)
                    s[qt] = __builtin_amdgcn_mfma_f32_16x16x32_bf16(af, Qf[qt][ks], s[qt], 0, 0, 0);
            }
            short4v pa[2];
            #pragma unroll
            for (int qt = 0; qt < 2; ++qt) {
                float4v p = s[qt] * s[qt];   // v_pk_mul_f32
                dacc[qt] += p;               // v_pk_add_f32
                union { uint2v u; short4v s; } cv;
                cv.u[0] = pack2(p[0], p[1]); cv.u[1] = pack2(p[2], p[3]);
                pa[qt] = cv.s;
            }
            #pragma unroll
            for (int nt = 0; nt < 4; ++nt) {
                short4v bf = *(const short4v*)&Vt[cur][nt*16 + c][mt*16 + qd*4];
                #pragma unroll
                for (int qt = 0; qt < 2; ++qt)
                    Oacc[qt][nt] = MFMA16(pa[qt], bf, Oacc[qt][nt]);
            }
        }
        __syncthreads();
    }

    // ---- denominator: full sum per q via cross-quad reduce ----
    #pragma unroll
    for (int qt = 0; qt < 2; ++qt) {
        float d = (dacc[qt][0] + dacc[qt][1]) + (dacc[qt][2] + dacc[qt][3]);
        d += __shfl_xor(d, 16);
        d += __shfl_xor(d, 32);
        if (qd == 0) Dn[wave][qt*16 + c] = d;
    }
    __syncthreads();

    // ---- epilogue ----
    #pragma unroll
    for (int qt = 0; qt < 2; ++qt) {
        #pragma unroll
        for (int r = 0; r < 4; ++r) {
            float inv = 1.0f / (Dn[wave][qt*16 + qd*4 + r] + EPS_F);
            float* dst = op + (size_t)(qw0 + qt*16 + qd*4 + r) * DHEAD + c;
            #pragma unroll
            for (int nt = 0; nt < 4; ++nt)
                dst[nt*16] = Oacc[qt][nt][r] * inv;
        }
    }
}

extern "C" void kernel_launch(void* const* d_in, const int* in_sizes, int n_in,
                              void* d_out, int out_size, void* d_ws, size_t ws_size,
                              hipStream_t stream) {
    const float* q = (const float*)d_in[0];
    const float* k = (const float*)d_in[1];
    const float* v = (const float*)d_in[2];
    float* out = (float*)d_out;
    dim3 grid((N_CTX / QBLK) * 64, 1, 1);   // 1024 blocks, swizzled in-kernel
    powsm_attn<<<grid, dim3(256, 1, 1), 0, stream>>>(q, k, v, out);
}